// Round 4
// baseline (577.503 us; speedup 1.0000x reference)
//
#include <hip/hip_runtime.h>

// Round 3 resubmit: rounds 1-3 all failed with UnresponsiveContainer (infra,
// same container instance each time). Kernel has never executed. Source
// unchanged from round 0 analysis:
//   - H0 stays zero in the reference loop -> R-branch dead,
//     concat([conv,H0])@Wl == conv@Wl_top, acc += probs[t]*(1-Z)*tanh(Ht)
//   - conv(x_t@W) == (A_norm@x_t)@W  -> aggregate raw (N,96) features ONCE,
//     then fold (..@W)@Wl_top into precomputed 8x64 Mz/Mh on device.

#define NN 50000
#define EE 1600000
#define FT 96        // F*T
#define TP 12
#define FF 8
#define HH 64
#define SCAN_P 512
#define CHUNK 98     // ceil(NN / SCAN_P)

__global__ void __launch_bounds__(256) k_init(float* deg, int* counts) {
    int n = blockIdx.x * 256 + threadIdx.x;
    if (n < NN) { deg[n] = 1.0f; counts[n] = 0; }
}

__global__ void __launch_bounds__(256) k_count(const int* ei, const float* ea,
                                               float* deg, int* counts) {
    int e = blockIdx.x * 256 + threadIdx.x;
    if (e < EE) {
        int d = ei[EE + e];
        atomicAdd(&deg[d], ea[e]);
        atomicAdd(&counts[d], 1);
    }
}

__global__ void __launch_bounds__(256) k_dinv(float* deg) {
    int n = blockIdx.x * 256 + threadIdx.x;
    if (n < NN) {
        float v = deg[n];
        deg[n] = (v > 0.0f) ? rsqrtf(v) : 0.0f;
    }
}

__global__ void __launch_bounds__(256) k_scan_part(const int* counts, int* psum) {
    int p = blockIdx.x * 256 + threadIdx.x;
    if (p >= SCAN_P) return;
    int s = 0, base = p * CHUNK;
    for (int i = 0; i < CHUNK; i++) {
        int n = base + i;
        if (n < NN) s += counts[n];
    }
    psum[p] = s;
}

__global__ void __launch_bounds__(SCAN_P) k_scan_total(int* psum) {
    __shared__ int sh[SCAN_P];
    int i = threadIdx.x;
    int orig = psum[i];
    sh[i] = orig;
    __syncthreads();
    for (int off = 1; off < SCAN_P; off <<= 1) {
        int v = (i >= off) ? sh[i - off] : 0;
        __syncthreads();
        sh[i] += v;
        __syncthreads();
    }
    psum[i] = sh[i] - orig;   // exclusive
}

__global__ void __launch_bounds__(256) k_scan_write(const int* counts, const int* psum,
                                                    int* rowptr, int* cursor) {
    int p = blockIdx.x * 256 + threadIdx.x;
    if (p >= SCAN_P) return;
    int off = psum[p];
    int base = p * CHUNK;
    for (int i = 0; i < CHUNK; i++) {
        int n = base + i;
        if (n < NN) { rowptr[n] = off; cursor[n] = off; off += counts[n]; }
    }
    if (p == SCAN_P - 1) rowptr[NN] = off;   // == EE
}

__global__ void __launch_bounds__(256) k_scatter(const int* ei, const float* ea,
                                                 const float* dinv, int* cursor, int2* csr) {
    int e = blockIdx.x * 256 + threadIdx.x;
    if (e < EE) {
        int s = ei[e], d = ei[EE + e];
        float wgt = dinv[s] * ea[e] * dinv[d];
        int pos = atomicAdd(&cursor[d], 1);
        csr[pos] = make_int2(s, __float_as_int(wgt));
    }
}

// fold: Mz = Wz @ Wlz_top (8x64), Mh = Wh @ Wlh_top, folded biases, probs = softmax(att)
__global__ void __launch_bounds__(64) k_fold(const float* Wz, const float* bz,
                                             const float* Wh, const float* bh,
                                             const float* Wlz, const float* blz,
                                             const float* Wlh, const float* blh,
                                             const float* att, float* fold) {
    int h = threadIdx.x;   // 0..63
    for (int f = 0; f < FF; f++) {
        float sz = 0.0f, sh = 0.0f;
        for (int k = 0; k < HH; k++) {
            sz += Wz[f * HH + k] * Wlz[k * HH + h];
            sh += Wh[f * HH + k] * Wlh[k * HH + h];
        }
        fold[f * HH + h]       = sz;   // Mz
        fold[512 + f * HH + h] = sh;   // Mh
    }
    float cz = blz[h], ch = blh[h];
    for (int k = 0; k < HH; k++) {
        cz += bz[k] * Wlz[k * HH + h];
        ch += bh[k] * Wlh[k * HH + h];
    }
    fold[1024 + h] = cz;
    fold[1088 + h] = ch;
    if (h < TP) {
        float m = -1e30f;
        for (int t = 0; t < TP; t++) m = fmaxf(m, att[t]);
        float s = 0.0f;
        for (int t = 0; t < TP; t++) s += __expf(att[t] - m);
        fold[1152 + h] = __expf(att[h] - m) / s;
    }
}

// one wave per node: agg[n,:] = dinv[n]^2 * x[n,:] + sum_e w_e * x[src_e,:]
__global__ void __launch_bounds__(256) k_agg(const float* __restrict__ x,
                                             const float* __restrict__ dinv,
                                             const int* __restrict__ rowptr,
                                             const int2* __restrict__ csr,
                                             float* __restrict__ agg) {
    int wave = threadIdx.x >> 6;
    int lane = threadIdx.x & 63;
    int n = blockIdx.x * 4 + wave;
    if (n >= NN) return;
    float di = dinv[n];
    float w0 = di * di;
    const float* xn = x + (size_t)n * FT;
    float acc0 = w0 * xn[lane];
    float acc1 = (lane < 32) ? w0 * xn[64 + lane] : 0.0f;
    int jb = rowptr[n], je = rowptr[n + 1];
    for (int j = jb; j < je; j++) {
        int2 m = csr[j];
        float wgt = __int_as_float(m.y);
        const float* xs = x + (size_t)m.x * FT;
        acc0 += wgt * xs[lane];
        if (lane < 32) acc1 += wgt * xs[64 + lane];
    }
    float* an = agg + (size_t)n * FT;
    an[lane] = acc0;
    if (lane < 32) an[64 + lane] = acc1;
}

// thread per node: fused Z/Ht/acc/relu/out
__global__ void __launch_bounds__(256) k_main(const float* __restrict__ agg,
                                              const float* __restrict__ fold,
                                              const float* __restrict__ Wout,
                                              const float* __restrict__ bout,
                                              float* __restrict__ out) {
    __shared__ float sMz[512], sMh[512], sczb[64], schb[64], sprobs[16], sWout[768], sbout[16];
    for (int i = threadIdx.x; i < 512; i += 256) { sMz[i] = fold[i]; sMh[i] = fold[512 + i]; }
    if (threadIdx.x < 64) {
        sczb[threadIdx.x] = fold[1024 + threadIdx.x];
        schb[threadIdx.x] = fold[1088 + threadIdx.x];
    }
    if (threadIdx.x < TP) {
        sprobs[threadIdx.x] = fold[1152 + threadIdx.x];
        sbout[threadIdx.x]  = bout[threadIdx.x];
    }
    for (int i = threadIdx.x; i < 768; i += 256) sWout[i] = Wout[i];
    __syncthreads();

    int n = blockIdx.x * 256 + threadIdx.x;
    if (n >= NN) return;

    float y[FT];
    const float4* ap = (const float4*)(agg + (size_t)n * FT);
    #pragma unroll
    for (int i = 0; i < FT / 4; i++) {
        float4 v = ap[i];
        y[4 * i] = v.x; y[4 * i + 1] = v.y; y[4 * i + 2] = v.z; y[4 * i + 3] = v.w;
    }

    float o[TP];
    #pragma unroll
    for (int j = 0; j < TP; j++) o[j] = sbout[j];

    for (int h = 0; h < HH; h++) {
        float zp[TP], hp[TP];
        float cz = sczb[h], ch = schb[h];
        #pragma unroll
        for (int t = 0; t < TP; t++) { zp[t] = cz; hp[t] = ch; }
        #pragma unroll
        for (int f = 0; f < FF; f++) {
            float mz = sMz[f * HH + h], mh = sMh[f * HH + h];
            #pragma unroll
            for (int t = 0; t < TP; t++) {
                zp[t] = fmaf(y[f * TP + t], mz, zp[t]);
                hp[t] = fmaf(y[f * TP + t], mh, hp[t]);
            }
        }
        float acc = 0.0f;
        #pragma unroll
        for (int t = 0; t < TP; t++) {
            float z = 1.0f / (1.0f + __expf(-zp[t]));
            float hv = fmaxf(hp[t], -30.0f);           // guard exp overflow in tanh
            float e = __expf(-2.0f * hv);
            float th = (1.0f - e) / (1.0f + e);
            acc += sprobs[t] * (1.0f - z) * th;
        }
        float r = fmaxf(acc, 0.0f);
        #pragma unroll
        for (int j = 0; j < TP; j++) o[j] = fmaf(r, sWout[h * TP + j], o[j]);
    }
    float* op = out + (size_t)n * TP;
    #pragma unroll
    for (int j = 0; j < TP; j++) op[j] = o[j];
}

extern "C" void kernel_launch(void* const* d_in, const int* in_sizes, int n_in,
                              void* d_out, int out_size, void* d_ws, size_t ws_size,
                              hipStream_t stream) {
    const float* x    = (const float*)d_in[0];
    const int*   ei   = (const int*)d_in[1];
    const float* ea   = (const float*)d_in[2];
    const float* Wz   = (const float*)d_in[3];
    const float* bz   = (const float*)d_in[4];
    // d_in[5], d_in[6] = Wr, br  (dead: H0 stays zero in the reference)
    const float* Wh   = (const float*)d_in[7];
    const float* bh   = (const float*)d_in[8];
    const float* Wlz  = (const float*)d_in[9];
    const float* blz  = (const float*)d_in[10];
    // d_in[11], d_in[12] = Wlr, blr (dead)
    const float* Wlh  = (const float*)d_in[13];
    const float* blh  = (const float*)d_in[14];
    const float* att  = (const float*)d_in[15];
    const float* Wout = (const float*)d_in[16];
    const float* bout = (const float*)d_in[17];
    float* out = (float*)d_out;

    char* w = (char*)d_ws;
    auto alloc = [&](size_t bytes) {
        char* p = w;
        w += (bytes + 255) & ~(size_t)255;
        return p;
    };
    float* deg    = (float*)alloc(NN * 4);            // becomes dinv in place
    int*   counts = (int*)alloc(NN * 4);
    int*   rowptr = (int*)alloc((NN + 1) * 4);
    int*   cursor = (int*)alloc(NN * 4);
    int2*  csr    = (int2*)alloc((size_t)EE * 8);
    float* agg    = (float*)alloc((size_t)NN * FT * 4);
    float* fold   = (float*)alloc(2048 * 4);
    int*   psum   = (int*)alloc(SCAN_P * 4);
    if ((size_t)(w - (char*)d_ws) > ws_size) return;  // ws too small -> visible failure

    hipLaunchKernelGGL(k_init,       dim3((NN + 255) / 256), dim3(256), 0, stream, deg, counts);
    hipLaunchKernelGGL(k_count,      dim3((EE + 255) / 256), dim3(256), 0, stream, ei, ea, deg, counts);
    hipLaunchKernelGGL(k_dinv,       dim3((NN + 255) / 256), dim3(256), 0, stream, deg);
    hipLaunchKernelGGL(k_scan_part,  dim3(2), dim3(256), 0, stream, counts, psum);
    hipLaunchKernelGGL(k_scan_total, dim3(1), dim3(SCAN_P), 0, stream, psum);
    hipLaunchKernelGGL(k_scan_write, dim3(2), dim3(256), 0, stream, counts, psum, rowptr, cursor);
    hipLaunchKernelGGL(k_scatter,    dim3((EE + 255) / 256), dim3(256), 0, stream, ei, ea, deg, cursor, csr);
    hipLaunchKernelGGL(k_fold,       dim3(1), dim3(64), 0, stream, Wz, bz, Wh, bh, Wlz, blz, Wlh, blh, att, fold);
    hipLaunchKernelGGL(k_agg,        dim3((NN + 3) / 4), dim3(256), 0, stream, x, deg, rowptr, csr, agg);
    hipLaunchKernelGGL(k_main,       dim3((NN + 255) / 256), dim3(256), 0, stream, agg, fold, Wout, bout, out);
}